// Round 9
// baseline (179.032 us; speedup 1.0000x reference)
//
#include <hip/hip_runtime.h>
#include <hip/hip_fp16.h>

#define Bsz 1024
#define Mm  2048
#define Rr  8192
#define EMAX 32   // ushort slots per E column (col nnz mean ~4.1)
#define SMAX 64   // ushort slots per S row    (row nnz mean ~16.4)

typedef unsigned short ushort_t;

// ---- pass 0: zero ecnt only (32 KB). ----
__global__ __launch_bounds__(256) void zero_ecnt(int* __restrict__ p) {
    p[blockIdx.x * 256 + threadIdx.x] = 0;       // grid 32 -> 8192
}

// ---- pass 1: blocks 0..511 transpose+log; 512..2559 E-scan (R5 form). ----
__global__ __launch_bounds__(256) void prep_kernel(
    const float* __restrict__ conc, const int* __restrict__ E,
    __half2* __restrict__ logcTh2, int* __restrict__ ecnt, ushort_t* __restrict__ elist)
{
    __shared__ int smem[64 * 65 + 1];            // transpose tile / escan buf+ctr
    const int bid = blockIdx.x;
    const int t   = threadIdx.x;

    if (bid < 512) {                             // ---- transpose + log -> fp16 ----
        float (*tile)[65] = (float(*)[65])smem;
        const int mt = (bid & 31) * 64;          // Mm/64 = 32
        const int bt = (bid >> 5) * 64;
        const int lm = t & 63;
        const int w  = t >> 6;
        for (int i = w; i < 64; i += 4)
            tile[lm][i] = __logf(conc[(size_t)(bt + i) * Mm + mt + lm]);
        __syncthreads();
        const int s       = bt >> 7;             // b-slice (128 b)
        const int colbase = (bt & 127) >> 1;
        __half2* dst = logcTh2 + (size_t)s * (Mm * 64);
        for (int idx = t; idx < 64 * 32; idx += 256) {
            const int j = idx >> 5, bp = idx & 31;
            dst[(mt + j) * 64 + colbase + bp] =
                __floats2half2_rn(tile[j][2 * bp], tile[j][2 * bp + 1]);
        }
    } else {                                     // ---- E-scan: owns row m ----
        const int m = bid - 512;
        int* buf = smem;
        int* nh  = smem + 256;
        if (t == 0) *nh = 0;
        __syncthreads();
        const int4* E4 = (const int4*)E + (size_t)m * 2048;
        int4 ev[8];
        #pragma unroll
        for (int u = 0; u < 8; ++u) ev[u] = E4[t + 256 * u];
        #pragma unroll
        for (int u = 0; u < 8; ++u) {
            const int r0 = (t + 256 * u) << 2;
            int v[4] = {ev[u].x, ev[u].y, ev[u].z, ev[u].w};
            #pragma unroll
            for (int q = 0; q < 4; ++q)
                if (v[q]) {
                    int i = atomicAdd(nh, 1);               // LDS atomic
                    if (i < 256) buf[i] = (v[q] << 13) | (r0 + q);
                }
        }
        __syncthreads();
        const int en = min(*nh, 256);
        if (t < en) {
            int wv = buf[t];
            int r  = wv & 0x1FFF;
            int e  = wv >> 13;
            int slot = atomicAdd(&ecnt[r], 1);              // ~16 atomics/block
            if (slot < EMAX) elist[r * EMAX + slot] = (ushort_t)((e << 11) | m);
        }
    }
}

// ---- pass 2 (fused): alternating groups of 8 blocks: S-scan | rates.
// rates gathers are wave-uniform rows x lane-contiguous 4B -> exactly the
// global_load_lds pattern (R3-validated on this harness). 32 rows staged
// per wave via fire-and-forget DMA (zero dest VGPRs -> depth can't be
// compiler-collapsed, the R2/R7 failure mode), one vmcnt(0), then
// conflict-free ds_read_b32 consumption.
__global__ __launch_bounds__(256, 4) void rs_kernel(
    const __half2* __restrict__ logcTh2, const float* __restrict__ kvec,
    const int* __restrict__ ecnt, const ushort_t* __restrict__ elist,
    const int* __restrict__ S, int* __restrict__ scnt, ushort_t* __restrict__ slist,
    __half2* __restrict__ VTh)
{
    __shared__ int smem[8192];                   // 32 KB: 4 waves x 32 x 256B stage
    const int bid   = blockIdx.x;                //        (S-scan aliases 1 KB)
    const int t     = threadIdx.x;
    const int grp   = bid >> 3;
    const int lane8 = bid & 7;

    if ((grp & 1) == 0) {                        // ---- S-scan: owns row m ----
        const int m = (grp >> 1) * 8 + lane8;    // even grps -> m in [0,2048)
        int* buf = smem;
        int* nh  = smem + 256;
        if (t == 0) *nh = 0;
        __syncthreads();
        const int4* S4 = (const int4*)S + (size_t)m * 2048;
        int4 sv[8];
        #pragma unroll
        for (int u = 0; u < 8; ++u) sv[u] = S4[t + 256 * u];
        #pragma unroll
        for (int u = 0; u < 8; ++u) {
            const int r0 = (t + 256 * u) << 2;
            int v[4] = {sv[u].x, sv[u].y, sv[u].z, sv[u].w};
            #pragma unroll
            for (int q = 0; q < 4; ++q)
                if (v[q]) {
                    int i = atomicAdd(nh, 1);               // LDS atomic
                    if (i < 256) buf[i] = ((v[q] + 2) << 13) | (r0 + q);
                }
        }
        __syncthreads();
        const int sn = min(*nh, SMAX);
        if (t == 0) scnt[m] = sn;
        if (t < SMAX)                            // write ALL slots: pads are safe
            slist[m * SMAX + t] = (t < sn) ? (ushort_t)buf[t]
                                           : (ushort_t)0x4000;   // enc 2 -> s=0
        return;
    }
    // ---- rates: VTh[s][r][64] = k[r]*exp(sum e*logcTh[s][m][64]) ----
    const int s   = lane8;                       // == blockIdx&7: XCD pin
    const int rch = grp >> 1;                    // odd grps -> 0..255, 32 r each
    const int col = t & 63;
    const int wr  = __builtin_amdgcn_readfirstlane(t >> 6);
    const __half2* lc = logcTh2 + (size_t)s * (Mm * 64);
    __half2* vt = VTh + (size_t)s * (Rr * 64);
    const int rb = rch * 32 + wr * 8;

    int  cnt[8]; int2 L0[8]; float kk[8];        // batch phase: independent s_loads
    #pragma unroll
    for (int i = 0; i < 8; ++i) {
        const int r = rb + i;
        cnt[i] = min(ecnt[r], EMAX);             // clamp: atomic counts can exceed slots
        L0[i]  = *(const int2*)(elist + (r << 5));
        kk[i]  = kvec[r];
    }
    char* st = (char*)smem + wr * 8192 / 4 * 4;  // per-wave 8 KB region
    st = (char*)smem + wr * 8192;
    float wg[32];
    #pragma unroll
    for (int i = 0; i < 8; ++i) {                // decode + stage: 32 DMAs in flight
        const unsigned wx = (unsigned)L0[i].x, wy = (unsigned)L0[i].y;
        const int m0_ = (int)(wx & 0x7FFu),  m1_ = (int)((wx >> 16) & 0x7FFu);
        const int m2_ = (int)(wy & 0x7FFu),  m3_ = (int)((wy >> 16) & 0x7FFu);
        wg[4 * i + 0] = (cnt[i] > 0) ? (float)((wx & 0xFFFFu) >> 11) : 0.f;
        wg[4 * i + 1] = (cnt[i] > 1) ? (float)(wx >> 27) : 0.f;
        wg[4 * i + 2] = (cnt[i] > 2) ? (float)((wy & 0xFFFFu) >> 11) : 0.f;
        wg[4 * i + 3] = (cnt[i] > 3) ? (float)(wy >> 27) : 0.f;
        __builtin_amdgcn_global_load_lds(
            (const __attribute__((address_space(1))) void*)(lc + m0_ * 64 + col),
            (__attribute__((address_space(3))) void*)(st + (4 * i + 0) * 256), 4, 0, 0);
        __builtin_amdgcn_global_load_lds(
            (const __attribute__((address_space(1))) void*)(lc + m1_ * 64 + col),
            (__attribute__((address_space(3))) void*)(st + (4 * i + 1) * 256), 4, 0, 0);
        __builtin_amdgcn_global_load_lds(
            (const __attribute__((address_space(1))) void*)(lc + m2_ * 64 + col),
            (__attribute__((address_space(3))) void*)(st + (4 * i + 2) * 256), 4, 0, 0);
        __builtin_amdgcn_global_load_lds(
            (const __attribute__((address_space(1))) void*)(lc + m3_ * 64 + col),
            (__attribute__((address_space(3))) void*)(st + (4 * i + 3) * 256), 4, 0, 0);
    }
    asm volatile("s_waitcnt vmcnt(0)" ::: "memory");
    __builtin_amdgcn_sched_barrier(0);
    float2 acc[8];
    #pragma unroll
    for (int i = 0; i < 8; ++i) {                // consume from LDS (conflict-free)
        float2 a = make_float2(0.f, 0.f);
        #pragma unroll
        for (int q = 0; q < 4; ++q) {
            const __half2 h = *(const __half2*)(st + (4 * i + q) * 256 + col * 4);
            const float2 gg = __half22float2(h);
            a.x += wg[4 * i + q] * gg.x;
            a.y += wg[4 * i + q] * gg.y;
        }
        acc[i] = a;
    }
    {   // rare wave-uniform tails (cnt > 4): register path
        unsigned w; float2 g; float v0, v1;
        #define EG2(word, c0, c1, A)                                           \
            w = (unsigned)(word);                                              \
            v0 = (c0) ? (float)((w & 0xFFFF) >> 11) : 0.f;                     \
            v1 = (c1) ? (float)(w >> 27) : 0.f;                                \
            g = __half22float2(lc[(w & 0x7FF) * 64 + col]);                    \
            A.x += v0 * g.x;  A.y += v0 * g.y;                                 \
            g = __half22float2(lc[((w >> 16) & 0x7FF) * 64 + col]);            \
            A.x += v1 * g.x;  A.y += v1 * g.y;
        #pragma unroll
        for (int i = 0; i < 8; ++i) {
            for (int j = 4; j < cnt[i]; j += 4) {
                int2 T = *(const int2*)(elist + ((rb + i) << 5) + j);
                EG2(T.x, j + 0 < cnt[i], j + 1 < cnt[i], acc[i])
                EG2(T.y, j + 2 < cnt[i], j + 3 < cnt[i], acc[i])
            }
        }
        #undef EG2
    }
    #pragma unroll
    for (int i = 0; i < 8; ++i)
        vt[(rb + i) * 64 + col] =
            __floats2half2_rn(kk[i] * __expf(acc[i].x), kk[i] * __expf(acc[i].y));
}

// ---- pass 3: out[b][m] = sum s*VTh[s][r][64]; DMA-staged 16-row batches. ----
__global__ __launch_bounds__(256, 4) void assemble_kernel(
    const __half2* __restrict__ VTh, const int* __restrict__ scnt,
    const ushort_t* __restrict__ slist, float* __restrict__ out)
{
    __shared__ float tile[128][17];              // [b-local][m-local] 8.5 KB
    __shared__ char  stg[4][4096];               // 4 waves x 16 x 256B stage
    const int s   = blockIdx.x & 7;              // same XCD pin as rates
    const int mch = blockIdx.x >> 3;             // 0..127, 16 m each
    const int col = threadIdx.x & 63;
    const int wm  = __builtin_amdgcn_readfirstlane(threadIdx.x >> 6);
    const __half2* vt = VTh + (size_t)s * (Rr * 64);
    const int m0 = mch * 16;

    int scn[4]; int4 W0[4], W1[4];               // batch phase: independent s_loads
    #pragma unroll
    for (int i = 0; i < 4; ++i) {
        const int m = m0 + i * 4 + wm;
        scn[i] = min(scnt[m], SMAX);
        W0[i]  = *(const int4*)(slist + (m << 6));
        W1[i]  = *(const int4*)(slist + (m << 6) + 8);
    }
    char* st = stg[wm];
    #pragma unroll
    for (int i = 0; i < 4; ++i) {
        const int ml = i * 4 + wm;
        const unsigned wd[8] = {(unsigned)W0[i].x, (unsigned)W0[i].y,
                                (unsigned)W0[i].z, (unsigned)W0[i].w,
                                (unsigned)W1[i].x, (unsigned)W1[i].y,
                                (unsigned)W1[i].z, (unsigned)W1[i].w};
        float swt[16];
        #pragma unroll
        for (int q = 0; q < 8; ++q) {            // decode + stage: 16 DMAs in flight
            const unsigned lo = wd[q] & 0xFFFFu, hi = wd[q] >> 16;
            swt[2 * q + 0] = (float)((int)(lo >> 13) - 2);   // pads -> 0
            swt[2 * q + 1] = (float)((int)(hi >> 13) - 2);
            __builtin_amdgcn_global_load_lds(
                (const __attribute__((address_space(1))) void*)(vt + (int)(lo & 0x1FFFu) * 64 + col),
                (__attribute__((address_space(3))) void*)(st + (2 * q + 0) * 256), 4, 0, 0);
            __builtin_amdgcn_global_load_lds(
                (const __attribute__((address_space(1))) void*)(vt + (int)(hi & 0x1FFFu) * 64 + col),
                (__attribute__((address_space(3))) void*)(st + (2 * q + 1) * 256), 4, 0, 0);
        }
        asm volatile("s_waitcnt vmcnt(0)" ::: "memory");
        __builtin_amdgcn_sched_barrier(0);
        float2 a = make_float2(0.f, 0.f);
        #pragma unroll
        for (int q = 0; q < 16; ++q) {           // consume from LDS
            const __half2 h = *(const __half2*)(st + q * 256 + col * 4);
            const float2 gg = __half22float2(h);
            a.x += swt[q] * gg.x;
            a.y += swt[q] * gg.y;
        }
        {   // rare tails (sn > 16); pads materialized -> safe groups
            unsigned w; float2 v; float sw;
            #define SG(word, A)                                                \
                w = (unsigned)(word);                                          \
                v = __half22float2(vt[(w & 0x1FFF) * 64 + col]);               \
                sw = (float)((int)((w & 0xFFFF) >> 13) - 2);                   \
                A.x += sw * v.x;  A.y += sw * v.y;                             \
                v = __half22float2(vt[((w >> 16) & 0x1FFF) * 64 + col]);       \
                sw = (float)((int)(w >> 29) - 2);                              \
                A.x += sw * v.x;  A.y += sw * v.y;
            for (int j = 16; j < scn[i]; j += 8) {
                int4 T = *(const int4*)(slist + ((m0 + ml) << 6) + j);
                SG(T.x, a) SG(T.y, a) SG(T.z, a) SG(T.w, a)
            }
            #undef SG
        }
        tile[2 * col][ml]     = a.x;
        tile[2 * col + 1][ml] = a.y;
    }
    __syncthreads();
    #pragma unroll
    for (int pass = 0; pass < 2; ++pass) {
        const int bl = (threadIdx.x >> 2) + pass * 64;
        const int fl = threadIdx.x & 3;
        float4 vv = *(const float4*)&tile[bl][fl * 4];
        *(float4*)(out + (size_t)(s * 128 + bl) * Mm + m0 + fl * 4) = vv;
    }
}

extern "C" void kernel_launch(void* const* d_in, const int* in_sizes, int n_in,
                              void* d_out, int out_size, void* d_ws, size_t ws_size,
                              hipStream_t stream) {
    const float* conc = (const float*)d_in[0];
    const int*   E    = (const int*)d_in[1];
    const int*   S    = (const int*)d_in[2];
    const float* kvec = (const float*)d_in[3];
    float* out = (float*)d_out;

    // ws: VTh fp16 (16 MB) | logcTh fp16 (4 MB) | ecnt | scnt | elist u16 | slist u16
    __half2* VTh     = (__half2*)d_ws;
    __half2* logcTh2 = (__half2*)((char*)d_ws + (size_t)Rr * Bsz * sizeof(__half));
    int*    ecnt     = (int*)((char*)logcTh2 + (size_t)Mm * Bsz * sizeof(__half));
    int*    scnt     = ecnt + Rr;
    ushort_t* elist  = (ushort_t*)(scnt + Mm);
    ushort_t* slist  = elist + Rr * EMAX;
    const size_t need = (size_t)Rr * Bsz * sizeof(__half)
                      + (size_t)Mm * Bsz * sizeof(__half)
                      + (size_t)(Rr + Mm) * sizeof(int)
                      + (size_t)(Rr * EMAX + Mm * SMAX) * sizeof(ushort_t);
    if (ws_size < need) return;

    zero_ecnt<<<32, 256, 0, stream>>>(ecnt);
    prep_kernel<<<2560, 256, 0, stream>>>(conc, E, logcTh2, ecnt, elist);
    rs_kernel<<<4096, 256, 0, stream>>>(logcTh2, kvec, ecnt, elist, S, scnt, slist, VTh);
    assemble_kernel<<<1024, 256, 0, stream>>>(VTh, scnt, slist, out);
}

// Round 10
// 174.581 us; speedup vs baseline: 1.0255x; 1.0255x over previous
//
#include <hip/hip_runtime.h>
#include <hip/hip_fp16.h>

#define Bsz 1024
#define Mm  2048
#define Rr  8192
#define EMAX 32   // ushort slots per E column (col nnz mean ~4.1)
#define SMAX 64   // ushort slots per S row    (row nnz mean ~16.4)

typedef unsigned short ushort_t;

// ---- pass 0: zero ecnt only (32 KB). ----
__global__ __launch_bounds__(256) void zero_ecnt(int* __restrict__ p) {
    p[blockIdx.x * 256 + threadIdx.x] = 0;       // grid 32 -> 8192
}

// ---- pass 1: blocks 0..511 transpose+log; 512..2559 row-style E-scan. ----
// Session-best structure (R5, 174.6us). Scan service rate ~2.3-2.6 TB/s is a
// measured wall (4 falsified engines: reg-dest x2, DMA, copy-sweep).
__global__ __launch_bounds__(256) void prep_kernel(
    const float* __restrict__ conc, const int* __restrict__ E,
    __half2* __restrict__ logcTh2, int* __restrict__ ecnt, ushort_t* __restrict__ elist)
{
    __shared__ int smem[64 * 65 + 1];            // transpose tile / escan buf+ctr
    const int bid = blockIdx.x;
    const int t   = threadIdx.x;

    if (bid < 512) {                             // ---- transpose + log -> fp16 ----
        float (*tile)[65] = (float(*)[65])smem;
        const int mt = (bid & 31) * 64;          // Mm/64 = 32
        const int bt = (bid >> 5) * 64;
        const int lm = t & 63;
        const int w  = t >> 6;
        for (int i = w; i < 64; i += 4)
            tile[lm][i] = __logf(conc[(size_t)(bt + i) * Mm + mt + lm]);
        __syncthreads();
        const int s       = bt >> 7;             // b-slice (128 b)
        const int colbase = (bt & 127) >> 1;
        __half2* dst = logcTh2 + (size_t)s * (Mm * 64);
        for (int idx = t; idx < 64 * 32; idx += 256) {
            const int j = idx >> 5, bp = idx & 31;
            dst[(mt + j) * 64 + colbase + bp] =
                __floats2half2_rn(tile[j][2 * bp], tile[j][2 * bp + 1]);
        }
    } else {                                     // ---- E-scan: owns row m ----
        const int m = bid - 512;
        int* buf = smem;
        int* nh  = smem + 256;
        if (t == 0) *nh = 0;
        __syncthreads();
        const int4* E4 = (const int4*)E + (size_t)m * 2048;
        int4 ev[8];
        #pragma unroll
        for (int u = 0; u < 8; ++u) ev[u] = E4[t + 256 * u];
        #pragma unroll
        for (int u = 0; u < 8; ++u) {
            const int r0 = (t + 256 * u) << 2;
            int v[4] = {ev[u].x, ev[u].y, ev[u].z, ev[u].w};
            #pragma unroll
            for (int q = 0; q < 4; ++q)
                if (v[q]) {
                    int i = atomicAdd(nh, 1);               // LDS atomic
                    if (i < 256) buf[i] = (v[q] << 13) | (r0 + q);
                }
        }
        __syncthreads();
        const int en = min(*nh, 256);
        if (t < en) {
            int wv = buf[t];
            int r  = wv & 0x1FFF;
            int e  = wv >> 13;
            int slot = atomicAdd(&ecnt[r], 1);              // ~16 atomics/block
            if (slot < EMAX) elist[r * EMAX + slot] = (ushort_t)((e << 11) | m);
        }
    }
}

// ---- pass 2 (fused): alternating groups of 8 blocks: S-scan | rates.
// S-scan feeds only assemble -> overlaps rates' latency wall. Group-of-8
// interleave keeps rates' s == blockIdx&7 XCD/L2 pin intact.
__global__ __launch_bounds__(256) void rs_kernel(
    const __half2* __restrict__ logcTh2, const float* __restrict__ kvec,
    const int* __restrict__ ecnt, const ushort_t* __restrict__ elist,
    const int* __restrict__ S, int* __restrict__ scnt, ushort_t* __restrict__ slist,
    __half2* __restrict__ VTh)
{
    __shared__ int smem[257];                    // S-scan buf+ctr (1 KB)
    const int bid   = blockIdx.x;
    const int t     = threadIdx.x;
    const int grp   = bid >> 3;
    const int lane8 = bid & 7;

    if ((grp & 1) == 0) {                        // ---- S-scan: owns row m ----
        const int m = (grp >> 1) * 8 + lane8;    // even grps -> m in [0,2048)
        int* buf = smem;
        int* nh  = smem + 256;
        if (t == 0) *nh = 0;
        __syncthreads();
        const int4* S4 = (const int4*)S + (size_t)m * 2048;
        int4 sv[8];
        #pragma unroll
        for (int u = 0; u < 8; ++u) sv[u] = S4[t + 256 * u];
        #pragma unroll
        for (int u = 0; u < 8; ++u) {
            const int r0 = (t + 256 * u) << 2;
            int v[4] = {sv[u].x, sv[u].y, sv[u].z, sv[u].w};
            #pragma unroll
            for (int q = 0; q < 4; ++q)
                if (v[q]) {
                    int i = atomicAdd(nh, 1);               // LDS atomic
                    if (i < 256) buf[i] = ((v[q] + 2) << 13) | (r0 + q);
                }
        }
        __syncthreads();
        const int sn = min(*nh, SMAX);
        if (t == 0) scnt[m] = sn;
        if (t < SMAX)                            // write ALL slots: pads are safe
            slist[m * SMAX + t] = (t < sn) ? (ushort_t)buf[t]
                                           : (ushort_t)0x4000;   // enc 2 -> s=0
        return;
    }
    // ---- rates: VTh[s][r][64] = k[r]*exp(sum e*logcTh[s][m][64]) ----
    const int s   = lane8;                       // == blockIdx&7: XCD pin
    const int rch = grp >> 1;                    // odd grps -> 0..255, 32 r each
    const int col = t & 63;
    const int wr  = __builtin_amdgcn_readfirstlane(t >> 6);
    const __half2* lc = logcTh2 + (size_t)s * (Mm * 64);
    __half2* vt = VTh + (size_t)s * (Rr * 64);
    const int rb = rch * 32 + wr * 8;

    int  cnt[8]; int2 L0[8]; float kk[8];        // batch phase: independent s_loads
    #pragma unroll
    for (int i = 0; i < 8; ++i) {
        const int r = rb + i;
        cnt[i] = min(ecnt[r], EMAX);             // clamp: atomic counts can exceed slots
        L0[i]  = *(const int2*)(elist + (r << 5));
        kk[i]  = kvec[r];
    }
    float2 acc[8];
    unsigned w; float2 g; float v0, v1;
    #define EG2(word, c0, c1, A)                                               \
        w = (unsigned)(word);                                                  \
        v0 = (c0) ? (float)((w & 0xFFFF) >> 11) : 0.f;                         \
        v1 = (c1) ? (float)(w >> 27) : 0.f;                                    \
        g = __half22float2(lc[(w & 0x7FF) * 64 + col]);                        \
        A.x += v0 * g.x;  A.y += v0 * g.y;                                     \
        g = __half22float2(lc[((w >> 16) & 0x7FF) * 64 + col]);                \
        A.x += v1 * g.x;  A.y += v1 * g.y;
    #pragma unroll
    for (int i = 0; i < 8; ++i) {                // 32 gathers, one dependency level
        acc[i] = make_float2(0.f, 0.f);
        EG2(L0[i].x, cnt[i] > 0, cnt[i] > 1, acc[i])
        EG2(L0[i].y, cnt[i] > 2, cnt[i] > 3, acc[i])
    }
    #pragma unroll
    for (int i = 0; i < 8; ++i) {                // rare wave-uniform tails
        for (int j = 4; j < cnt[i]; j += 4) {
            int2 T = *(const int2*)(elist + ((rb + i) << 5) + j);
            EG2(T.x, j + 0 < cnt[i], j + 1 < cnt[i], acc[i])
            EG2(T.y, j + 2 < cnt[i], j + 3 < cnt[i], acc[i])
        }
    }
    #undef EG2
    #pragma unroll
    for (int i = 0; i < 8; ++i)
        vt[(rb + i) * 64 + col] =
            __floats2half2_rn(kk[i] * __expf(acc[i].x), kk[i] * __expf(acc[i].y));
}

// ---- pass 3: out[b][m] = sum s*VTh[s][r][64]; batched lists; LDS transpose stores ----
__global__ __launch_bounds__(256) void assemble_kernel(
    const __half2* __restrict__ VTh, const int* __restrict__ scnt,
    const ushort_t* __restrict__ slist, float* __restrict__ out)
{
    __shared__ float tile[128][17];              // [b-local][m-local] 8.5 KB
    const int s   = blockIdx.x & 7;              // same XCD pin as rates
    const int mch = blockIdx.x >> 3;             // 0..127, 16 m each
    const int col = threadIdx.x & 63;
    const int wm  = __builtin_amdgcn_readfirstlane(threadIdx.x >> 6);
    const __half2* vt = VTh + (size_t)s * (Rr * 64);
    const int m0 = mch * 16;

    int scn[4]; int4 W0[4], W1[4];               // batch phase: independent s_loads
    #pragma unroll
    for (int i = 0; i < 4; ++i) {
        const int m = m0 + i * 4 + wm;
        scn[i] = min(scnt[m], SMAX);
        W0[i]  = *(const int4*)(slist + (m << 6));
        W1[i]  = *(const int4*)(slist + (m << 6) + 8);
    }
    unsigned w; float2 v; float sw;
    #define SG(word, A)                                                        \
        w = (unsigned)(word);                                                  \
        v = __half22float2(vt[(w & 0x1FFF) * 64 + col]);                       \
        sw = (float)((int)((w & 0xFFFF) >> 13) - 2);                           \
        A.x += sw * v.x;  A.y += sw * v.y;                                     \
        v = __half22float2(vt[((w >> 16) & 0x1FFF) * 64 + col]);               \
        sw = (float)((int)(w >> 29) - 2);                                      \
        A.x += sw * v.x;  A.y += sw * v.y;
    #pragma unroll
    for (int i = 0; i < 4; ++i) {
        const int ml = i * 4 + wm;
        float2 a = make_float2(0.f, 0.f);
        SG(W0[i].x, a) SG(W0[i].y, a) SG(W0[i].z, a) SG(W0[i].w, a)
        SG(W1[i].x, a) SG(W1[i].y, a) SG(W1[i].z, a) SG(W1[i].w, a)
        for (int j = 16; j < scn[i]; j += 8) {   // pads materialized -> safe groups
            int4 T = *(const int4*)(slist + ((m0 + ml) << 6) + j);
            SG(T.x, a) SG(T.y, a) SG(T.z, a) SG(T.w, a)
        }
        tile[2 * col][ml]     = a.x;
        tile[2 * col + 1][ml] = a.y;
    }
    #undef SG
    __syncthreads();
    #pragma unroll
    for (int pass = 0; pass < 2; ++pass) {
        const int bl = (threadIdx.x >> 2) + pass * 64;
        const int fl = threadIdx.x & 3;
        float4 vv = *(const float4*)&tile[bl][fl * 4];
        *(float4*)(out + (size_t)(s * 128 + bl) * Mm + m0 + fl * 4) = vv;
    }
}

extern "C" void kernel_launch(void* const* d_in, const int* in_sizes, int n_in,
                              void* d_out, int out_size, void* d_ws, size_t ws_size,
                              hipStream_t stream) {
    const float* conc = (const float*)d_in[0];
    const int*   E    = (const int*)d_in[1];
    const int*   S    = (const int*)d_in[2];
    const float* kvec = (const float*)d_in[3];
    float* out = (float*)d_out;

    // ws: VTh fp16 (16 MB) | logcTh fp16 (4 MB) | ecnt | scnt | elist u16 | slist u16
    __half2* VTh     = (__half2*)d_ws;
    __half2* logcTh2 = (__half2*)((char*)d_ws + (size_t)Rr * Bsz * sizeof(__half));
    int*    ecnt     = (int*)((char*)logcTh2 + (size_t)Mm * Bsz * sizeof(__half));
    int*    scnt     = ecnt + Rr;
    ushort_t* elist  = (ushort_t*)(scnt + Mm);
    ushort_t* slist  = elist + Rr * EMAX;
    const size_t need = (size_t)Rr * Bsz * sizeof(__half)
                      + (size_t)Mm * Bsz * sizeof(__half)
                      + (size_t)(Rr + Mm) * sizeof(int)
                      + (size_t)(Rr * EMAX + Mm * SMAX) * sizeof(ushort_t);
    if (ws_size < need) return;

    zero_ecnt<<<32, 256, 0, stream>>>(ecnt);
    prep_kernel<<<2560, 256, 0, stream>>>(conc, E, logcTh2, ecnt, elist);
    rs_kernel<<<4096, 256, 0, stream>>>(logcTh2, kvec, ecnt, elist, S, scnt, slist, VTh);
    assemble_kernel<<<1024, 256, 0, stream>>>(VTh, scnt, slist, out);
}